// Round 5
// baseline (290.057 us; speedup 1.0000x reference)
//
#include <hip/hip_runtime.h>
#include <math.h>

#define DEG_EPS 1e-12f
#define LN_EPS  1e-5f

// ---------------------------------------------------------------------------
// ws layout (8-byte aligned first):
//   packed : N * 8   (bits [55:40] = edge count, bits [39:0] = sum(ew)*2^24)
//   meta   : E * 8   (int2 {col, bitcast(nw)})
//   ord    : E * 4   (within-row ordinal of each edge, from atomic return)
//   dis    : N * 4   (rsqrt(deg+eps))
//   rowptr : (N+1)*4
//   bsums  : NB * 4
//   boffs  : NB * 4
// ---------------------------------------------------------------------------

__global__ __launch_bounds__(256) void k_init(unsigned long long* __restrict__ packed,
                                              int N) {
    int i = blockIdx.x * blockDim.x + threadIdx.x;
    if (i < N) packed[i] = 0ULL;
}

// one 64-bit atomic per edge: count + fixed-point deg; return gives ordinal
__global__ __launch_bounds__(256) void k_count_deg(const int* __restrict__ rows,
                                                   const float* __restrict__ ew,
                                                   unsigned long long* __restrict__ packed,
                                                   unsigned* __restrict__ ord, int E) {
    int e = blockIdx.x * blockDim.x + threadIdx.x;
    if (e < E) {
        int r = rows[e];
        unsigned long long fx = (unsigned long long)__float2uint_rn(ew[e] * 16777216.0f);
        unsigned long long old = atomicAdd(&packed[r], (1ULL << 40) | fx);
        ord[e] = (unsigned)(old >> 40);
    }
}

// per-block (1024 rows) count reduction -> bsums
__global__ __launch_bounds__(256) void k_scan1(const unsigned long long* __restrict__ packed,
                                               int* __restrict__ bsums, int N) {
    __shared__ int sc[256];
    int t = threadIdx.x, b = blockIdx.x;
    int base = b * 1024 + t * 4;
    int s = 0;
#pragma unroll
    for (int k = 0; k < 4; ++k) {
        int i = base + k;
        if (i < N) s += (int)(packed[i] >> 40);
    }
    sc[t] = s; __syncthreads();
    for (int off = 128; off > 0; off >>= 1) {
        if (t < off) sc[t] += sc[t + off];
        __syncthreads();
    }
    if (t == 0) bsums[b] = sc[0];
}

// serial exclusive scan of block sums (NB ~ 98)
__global__ void k_scan2(const int* __restrict__ bsums, int* __restrict__ boffs,
                        int* __restrict__ rowptr, int NB, int N) {
    if (threadIdx.x == 0 && blockIdx.x == 0) {
        int run = 0;
        for (int b = 0; b < NB; ++b) { boffs[b] = run; run += bsums[b]; }
        rowptr[N] = run;   // == E
    }
}

// block scan -> rowptr (exclusive); dis = rsqrt(deg+eps) from packed low bits
__global__ __launch_bounds__(256) void k_scan3(const unsigned long long* __restrict__ packed,
                                               const int* __restrict__ boffs,
                                               int* __restrict__ rowptr,
                                               float* __restrict__ dis, int N) {
    __shared__ int sc[256];
    int t = threadIdx.x, b = blockIdx.x;
    int base = b * 1024 + t * 4;
    int c[4]; int s = 0;
#pragma unroll
    for (int k = 0; k < 4; ++k) {
        int i = base + k;
        unsigned long long p = (i < N) ? packed[i] : 0ULL;
        c[k] = (int)(p >> 40);
        s += c[k];
        if (i < N) {
            double deg = 1.0 + (double)(p & 0xFFFFFFFFFFULL) * (1.0 / 16777216.0);
            dis[i] = rsqrtf((float)deg + DEG_EPS);
        }
    }
    sc[t] = s; __syncthreads();
    int mySum = s;
    for (int off = 1; off < 256; off <<= 1) {
        int v = (t >= off) ? sc[t - off] : 0;
        __syncthreads();
        sc[t] += v;
        __syncthreads();
    }
    int run = sc[t] - mySum + boffs[b];
#pragma unroll
    for (int k = 0; k < 4; ++k) {
        int i = base + k;
        if (i < N) rowptr[i] = run;
        run += c[k];
    }
}

// fill CSR — atomic-free: slot = rowptr[r] + ord[e]
__global__ __launch_bounds__(256) void k_fill(const int* __restrict__ rows,
                                              const int* __restrict__ cols,
                                              const float* __restrict__ ew,
                                              const unsigned* __restrict__ ord,
                                              const float* __restrict__ dis,
                                              const int* __restrict__ rowptr,
                                              int2* __restrict__ meta, int E) {
    int e = blockIdx.x * blockDim.x + threadIdx.x;
    if (e < E) {
        int r = rows[e], c = cols[e];
        float nw = ew[e] * dis[r] * dis[c];
        int slot = rowptr[r] + (int)ord[e];
        meta[slot] = make_int2(c, __float_as_int(nw));
    }
}

// SpMM gather: one wave per row, lane = feature. No atomics.
__global__ __launch_bounds__(256) void k_spmm_csr(const int* __restrict__ rowptr,
                                                  const int2* __restrict__ meta,
                                                  const float* __restrict__ dis,
                                                  const float* __restrict__ x,
                                                  float* __restrict__ h, int N) {
    int t = blockIdx.x * blockDim.x + threadIdx.x;
    int row = t >> 6;
    if (row >= N) return;
    int lane = t & 63;

    float s = dis[row];                       // wave-uniform
    float acc = x[row * 64 + lane] * (s * s); // self loop: x / (deg+eps)

    int start = rowptr[row], end = rowptr[row + 1];
    for (int base = start; base < end; base += 64) {
        int rem = end - base;
        int cnt = rem < 64 ? rem : 64;
        int2 m = make_int2(0, 0);
        if (lane < rem) m = meta[base + lane];   // 64 edges in one coalesced load
        int j = 0;
        for (; j + 4 <= cnt; j += 4) {
            int   c0 = __shfl(m.x, j + 0, 64);
            float w0 = __int_as_float(__shfl(m.y, j + 0, 64));
            int   c1 = __shfl(m.x, j + 1, 64);
            float w1 = __int_as_float(__shfl(m.y, j + 1, 64));
            int   c2 = __shfl(m.x, j + 2, 64);
            float w2 = __int_as_float(__shfl(m.y, j + 2, 64));
            int   c3 = __shfl(m.x, j + 3, 64);
            float w3 = __int_as_float(__shfl(m.y, j + 3, 64));
            float v0 = x[c0 * 64 + lane];
            float v1 = x[c1 * 64 + lane];
            float v2 = x[c2 * 64 + lane];
            float v3 = x[c3 * 64 + lane];
            acc = fmaf(v0, w0, acc);
            acc = fmaf(v1, w1, acc);
            acc = fmaf(v2, w2, acc);
            acc = fmaf(v3, w3, acc);
        }
        for (; j < cnt; ++j) {
            int   c = __shfl(m.x, j, 64);
            float w = __int_as_float(__shfl(m.y, j, 64));
            acc = fmaf(x[c * 64 + lane], w, acc);
        }
    }
    h[row * 64 + lane] = acc;
}

// ---------------------------------------------------------------------------
// Epilogue v3: y = gelu(h@W^T + b); LN(y)*gamma+beta + x  (in-place on d_out)
//   - lane = node; each lane holds its node's full h row in 64 VGPRs
//   - W/bias/gamma/beta read with wave-uniform indices -> scalar (K$) loads,
//     zero DS-pipe traffic (v2 was LDS-pipe-bound on W broadcasts)
//   - 2 waves split the 64 output features per 64-node tile (32 each);
//     LN stats combined via 2 KB LDS + one barrier
// ---------------------------------------------------------------------------
__global__ __launch_bounds__(256) void k_epilogue(
    const float4* __restrict__ x4, const float4* __restrict__ W4,
    const float* __restrict__ bias, const float4* __restrict__ g4,
    const float4* __restrict__ bt4, float* __restrict__ h, int N)
{
    __shared__ float psum[2][2][64];
    __shared__ float psq[2][2][64];
    const int tid  = threadIdx.x;
    const int wv   = tid >> 6;
    const int lane = tid & 63;
    const int t    = wv >> 1;   // tile in block (0..1)
    const int p    = wv & 1;    // output-feature half (0..1)
    const int i0   = (blockIdx.x * 2 + t) * 64;
    const int node = i0 + lane;
    const bool valid = node < N;
    const float4* h4 = (const float4*)h;
    float4* out4 = (float4*)h;

    // lane's h row, straight from global (L2-warm from k_spmm_csr)
    float hr[64];
    if (valid) {
#pragma unroll
        for (int q = 0; q < 16; ++q) {
            float4 v = h4[(size_t)node * 16 + q];
            hr[q * 4 + 0] = v.x; hr[q * 4 + 1] = v.y;
            hr[q * 4 + 2] = v.z; hr[q * 4 + 3] = v.w;
        }
    } else {
#pragma unroll
        for (int k = 0; k < 64; ++k) hr[k] = 0.f;
    }

    // 32 output features for this half; W via uniform (scalar-cache) loads
    float a[32];
    float sum = 0.f, ssq = 0.f;
#pragma unroll
    for (int j = 0; j < 32; ++j) {
        const int jj = p * 32 + j;             // wave-uniform
        float acc = bias[jj];
#pragma unroll
        for (int q = 0; q < 16; ++q) {
            float4 w = W4[jj * 16 + q];        // uniform -> s_load_dwordx4
            acc = fmaf(hr[q * 4 + 0], w.x, acc);
            acc = fmaf(hr[q * 4 + 1], w.y, acc);
            acc = fmaf(hr[q * 4 + 2], w.z, acc);
            acc = fmaf(hr[q * 4 + 3], w.w, acc);
        }
        acc = 0.5f * acc * (1.0f + erff(acc * 0.70710678118654752f));
        a[j] = acc;
        sum += acc; ssq += acc * acc;
    }
    psum[t][p][lane] = sum;
    psq[t][p][lane]  = ssq;
    __syncthreads();
    float S = psum[t][0][lane] + psum[t][1][lane];
    float Q = psq[t][0][lane]  + psq[t][1][lane];
    float m  = S * (1.0f / 64.0f);
    float var = fmaxf(Q * (1.0f / 64.0f) - m * m, 0.0f);
    float rs = rsqrtf(var + LN_EPS);

    if (valid) {
#pragma unroll
        for (int q = 0; q < 8; ++q) {
            int jq = p * 8 + q;                 // float4 index in feature dim
            float4 gg = g4[jq], bb = bt4[jq];   // uniform
            float4 xx = x4[(size_t)node * 16 + jq];
            float4 o;
            o.x = (a[q * 4 + 0] - m) * rs * gg.x + bb.x + xx.x;
            o.y = (a[q * 4 + 1] - m) * rs * gg.y + bb.y + xx.y;
            o.z = (a[q * 4 + 2] - m) * rs * gg.z + bb.z + xx.z;
            o.w = (a[q * 4 + 3] - m) * rs * gg.w + bb.w + xx.w;
            out4[(size_t)node * 16 + jq] = o;
        }
    }
}

// ---------------------------------------------------------------------------
extern "C" void kernel_launch(void* const* d_in, const int* in_sizes, int n_in,
                              void* d_out, int out_size, void* d_ws, size_t ws_size,
                              hipStream_t stream) {
    const float* x   = (const float*)d_in[0];
    const int*   ei  = (const int*)  d_in[1];   // [2,E] flat: rows then cols
    const float* ew  = (const float*)d_in[2];
    const float* W   = (const float*)d_in[3];
    const float* b   = (const float*)d_in[4];
    const float* g   = (const float*)d_in[5];
    const float* bt  = (const float*)d_in[6];
    float* out = (float*)d_out;

    const int N = in_sizes[0] / 64;
    const int E = in_sizes[1] / 2;
    const int* rows = ei;
    const int* cols = ei + E;
    const int NB = (N + 1023) / 1024;

    // ws carve-up (8-byte aligned members first)
    char* w8 = (char*)d_ws;
    unsigned long long* packed = (unsigned long long*)w8; w8 += (size_t)N * 8;
    int2*     meta   = (int2*)w8;                         w8 += (size_t)E * 8;
    unsigned* ord    = (unsigned*)w8;                     w8 += (size_t)E * 4;
    float*    dis    = (float*)w8;                        w8 += (size_t)N * 4;
    int*      rowptr = (int*)w8;                          w8 += (size_t)(N + 1) * 4;
    int*      bsums  = (int*)w8;                          w8 += (size_t)NB * 4;
    int*      boffs  = (int*)w8;

    k_init<<<(N + 255) / 256, 256, 0, stream>>>(packed, N);
    k_count_deg<<<(E + 255) / 256, 256, 0, stream>>>(rows, ew, packed, ord, E);
    k_scan1<<<NB, 256, 0, stream>>>(packed, bsums, N);
    k_scan2<<<1, 64, 0, stream>>>(bsums, boffs, rowptr, NB, N);
    k_scan3<<<NB, 256, 0, stream>>>(packed, boffs, rowptr, dis, N);
    k_fill<<<(E + 255) / 256, 256, 0, stream>>>(rows, cols, ew, ord, dis,
                                                rowptr, meta, E);
    long total = (long)N * 64;
    k_spmm_csr<<<(int)((total + 255) / 256), 256, 0, stream>>>(
        rowptr, meta, dis, x, out, N);

    int tiles = (N + 63) / 64;         // 64-node tiles
    int eblocks = (tiles + 1) / 2;     // 2 tiles per block (2 waves each)
    k_epilogue<<<eblocks, 256, 0, stream>>>(
        (const float4*)x, (const float4*)W, b, (const float4*)g,
        (const float4*)bt, out, N);
}

// Round 6
// 268.210 us; speedup vs baseline: 1.0815x; 1.0815x over previous
//
#include <hip/hip_runtime.h>
#include <math.h>

#define DEG_EPS 1e-12f
#define LN_EPS  1e-5f

// ---------------------------------------------------------------------------
// ws layout (8-byte aligned first):
//   packed : N * 8       (bits [55:40] = edge count, bits [39:0] = sum(ew)*2^24)
//   meta   : E * 8       (int2 {col, bitcast(nw)})
//   xwb    : N * 64 * 2  (bf16 xw = x @ W^T)
//   ord    : E * 4       (within-row ordinal of each edge)
//   dis    : N * 4       (rsqrt(deg+eps))
//   rowptr : (N+1)*4
//   bsums  : NB * 4
//   boffs  : NB * 4
// ---------------------------------------------------------------------------

__global__ __launch_bounds__(256) void k_init(unsigned long long* __restrict__ packed,
                                              int N) {
    int i = blockIdx.x * blockDim.x + threadIdx.x;
    if (i < N) packed[i] = 0ULL;
}

// one 64-bit atomic per edge: count + fixed-point deg; return gives ordinal
__global__ __launch_bounds__(256) void k_count_deg(const int* __restrict__ rows,
                                                   const float* __restrict__ ew,
                                                   unsigned long long* __restrict__ packed,
                                                   unsigned* __restrict__ ord, int E) {
    int e = blockIdx.x * blockDim.x + threadIdx.x;
    if (e < E) {
        int r = rows[e];
        unsigned long long fx = (unsigned long long)__float2uint_rn(ew[e] * 16777216.0f);
        unsigned long long old = atomicAdd(&packed[r], (1ULL << 40) | fx);
        ord[e] = (unsigned)(old >> 40);
    }
}

// per-block (1024 rows) count reduction -> bsums
__global__ __launch_bounds__(256) void k_scan1(const unsigned long long* __restrict__ packed,
                                               int* __restrict__ bsums, int N) {
    __shared__ int sc[256];
    int t = threadIdx.x, b = blockIdx.x;
    int base = b * 1024 + t * 4;
    int s = 0;
#pragma unroll
    for (int k = 0; k < 4; ++k) {
        int i = base + k;
        if (i < N) s += (int)(packed[i] >> 40);
    }
    sc[t] = s; __syncthreads();
    for (int off = 128; off > 0; off >>= 1) {
        if (t < off) sc[t] += sc[t + off];
        __syncthreads();
    }
    if (t == 0) bsums[b] = sc[0];
}

// serial exclusive scan of block sums (NB ~ 98)
__global__ void k_scan2(const int* __restrict__ bsums, int* __restrict__ boffs,
                        int* __restrict__ rowptr, int NB, int N) {
    if (threadIdx.x == 0 && blockIdx.x == 0) {
        int run = 0;
        for (int b = 0; b < NB; ++b) { boffs[b] = run; run += bsums[b]; }
        rowptr[N] = run;   // == E
    }
}

// block scan -> rowptr (exclusive); dis = rsqrt(deg+eps) from packed low bits
__global__ __launch_bounds__(256) void k_scan3(const unsigned long long* __restrict__ packed,
                                               const int* __restrict__ boffs,
                                               int* __restrict__ rowptr,
                                               float* __restrict__ dis, int N) {
    __shared__ int sc[256];
    int t = threadIdx.x, b = blockIdx.x;
    int base = b * 1024 + t * 4;
    int c[4]; int s = 0;
#pragma unroll
    for (int k = 0; k < 4; ++k) {
        int i = base + k;
        unsigned long long p = (i < N) ? packed[i] : 0ULL;
        c[k] = (int)(p >> 40);
        s += c[k];
        if (i < N) {
            double deg = 1.0 + (double)(p & 0xFFFFFFFFFFULL) * (1.0 / 16777216.0);
            dis[i] = rsqrtf((float)deg + DEG_EPS);
        }
    }
    sc[t] = s; __syncthreads();
    int mySum = s;
    for (int off = 1; off < 256; off <<= 1) {
        int v = (t >= off) ? sc[t - off] : 0;
        __syncthreads();
        sc[t] += v;
        __syncthreads();
    }
    int run = sc[t] - mySum + boffs[b];
#pragma unroll
    for (int k = 0; k < 4; ++k) {
        int i = base + k;
        if (i < N) rowptr[i] = run;
        run += c[k];
    }
}

// fill CSR — atomic-free: slot = rowptr[r] + ord[e]
__global__ __launch_bounds__(256) void k_fill(const int* __restrict__ rows,
                                              const int* __restrict__ cols,
                                              const float* __restrict__ ew,
                                              const unsigned* __restrict__ ord,
                                              const float* __restrict__ dis,
                                              const int* __restrict__ rowptr,
                                              int2* __restrict__ meta, int E) {
    int e = blockIdx.x * blockDim.x + threadIdx.x;
    if (e < E) {
        int r = rows[e], c = cols[e];
        float nw = ew[e] * dis[r] * dis[c];
        int slot = rowptr[r] + (int)ord[e];
        meta[slot] = make_int2(c, __float_as_int(nw));
    }
}

// ---------------------------------------------------------------------------
// xw = x @ W^T  (fp32 in, bf16 out).  Lane = output feature j.
//   - lane j holds W[j][0..63] in 64 VGPRs (loaded once per wave)
//   - x-row address is wave-uniform (readfirstlane) -> scalar s_loads,
//     FMA reads the SGPR operand directly: zero DS traffic, no divergence
// ---------------------------------------------------------------------------
__global__ __launch_bounds__(256) void k_xw(const float* __restrict__ x,
                                            const float* __restrict__ W,
                                            unsigned short* __restrict__ xwb,
                                            int N, int rows_per_wave) {
    const int lane = threadIdx.x & 63;
    const int wave = (blockIdx.x * 256 + threadIdx.x) >> 6;

    // W row for this lane -> VGPRs
    float wl[64];
    {
        const float4* w4 = (const float4*)(W + lane * 64);
#pragma unroll
        for (int q = 0; q < 16; ++q) {
            float4 v = w4[q];
            wl[q * 4 + 0] = v.x; wl[q * 4 + 1] = v.y;
            wl[q * 4 + 2] = v.z; wl[q * 4 + 3] = v.w;
        }
    }

    int n0 = __builtin_amdgcn_readfirstlane(wave * rows_per_wave);
    int n1 = n0 + rows_per_wave;
    if (n1 > N) n1 = N;

    for (int n = n0; n < n1; ++n) {
        const float* xr = x + (size_t)__builtin_amdgcn_readfirstlane(n) * 64;
        float a0 = 0.f, a1 = 0.f, a2 = 0.f, a3 = 0.f;   // 4-way ILP chains
#pragma unroll
        for (int k = 0; k < 64; k += 4) {
            a0 = fmaf(xr[k + 0], wl[k + 0], a0);
            a1 = fmaf(xr[k + 1], wl[k + 1], a1);
            a2 = fmaf(xr[k + 2], wl[k + 2], a2);
            a3 = fmaf(xr[k + 3], wl[k + 3], a3);
        }
        float acc = (a0 + a1) + (a2 + a3);
        // fp32 -> bf16 RNE
        unsigned u = __float_as_uint(acc);
        u += 0x7FFF + ((u >> 16) & 1);
        xwb[(size_t)n * 64 + lane] = (unsigned short)(u >> 16);
    }
}

// ---------------------------------------------------------------------------
// Fused SpMM + bias + GELU + LayerNorm + residual.  One wave per row.
//   z[row][lane] = s^2*xw[row][lane] + sum_e nw_e * xw[col_e][lane]
//   out = LN(gelu(z + b)) * gamma + beta + x
// ---------------------------------------------------------------------------
__global__ __launch_bounds__(256) void k_spmm_fused(
    const int* __restrict__ rowptr, const int2* __restrict__ meta,
    const float* __restrict__ dis, const unsigned short* __restrict__ xwb,
    const float* __restrict__ x, const float* __restrict__ bias,
    const float* __restrict__ gamma, const float* __restrict__ beta,
    float* __restrict__ out, int N)
{
    int t = blockIdx.x * blockDim.x + threadIdx.x;
    int row = t >> 6;
    if (row >= N) return;
    int lane = t & 63;

    float s = dis[row];   // wave-uniform
    float acc = __uint_as_float((unsigned)xwb[(size_t)row * 64 + lane] << 16) * (s * s);

    int start = rowptr[row], end = rowptr[row + 1];
    for (int base = start; base < end; base += 64) {
        int rem = end - base;
        int cnt = rem < 64 ? rem : 64;
        int2 m = make_int2(0, 0);
        if (lane < rem) m = meta[base + lane];   // 64 edges, one coalesced load
        int j = 0;
        for (; j + 4 <= cnt; j += 4) {
            int   c0 = __shfl(m.x, j + 0, 64);
            float w0 = __int_as_float(__shfl(m.y, j + 0, 64));
            int   c1 = __shfl(m.x, j + 1, 64);
            float w1 = __int_as_float(__shfl(m.y, j + 1, 64));
            int   c2 = __shfl(m.x, j + 2, 64);
            float w2 = __int_as_float(__shfl(m.y, j + 2, 64));
            int   c3 = __shfl(m.x, j + 3, 64);
            float w3 = __int_as_float(__shfl(m.y, j + 3, 64));
            float v0 = __uint_as_float((unsigned)xwb[(size_t)c0 * 64 + lane] << 16);
            float v1 = __uint_as_float((unsigned)xwb[(size_t)c1 * 64 + lane] << 16);
            float v2 = __uint_as_float((unsigned)xwb[(size_t)c2 * 64 + lane] << 16);
            float v3 = __uint_as_float((unsigned)xwb[(size_t)c3 * 64 + lane] << 16);
            acc = fmaf(v0, w0, acc);
            acc = fmaf(v1, w1, acc);
            acc = fmaf(v2, w2, acc);
            acc = fmaf(v3, w3, acc);
        }
        for (; j < cnt; ++j) {
            int   c = __shfl(m.x, j, 64);
            float w = __int_as_float(__shfl(m.y, j, 64));
            acc = fmaf(__uint_as_float((unsigned)xwb[(size_t)c * 64 + lane] << 16),
                       w, acc);
        }
    }

    // --- fused epilogue, all in-wave ---
    float a = acc + bias[lane];
    a = 0.5f * a * (1.0f + erff(a * 0.70710678118654752f));   // exact gelu

    float sum = a, ssq = a * a;
#pragma unroll
    for (int mk = 1; mk < 64; mk <<= 1) {
        sum += __shfl_xor(sum, mk, 64);
        ssq += __shfl_xor(ssq, mk, 64);
    }
    float mean = sum * (1.0f / 64.0f);
    float var  = fmaxf(ssq * (1.0f / 64.0f) - mean * mean, 0.0f);
    float rs   = rsqrtf(var + LN_EPS);

    out[(size_t)row * 64 + lane] =
        (a - mean) * rs * gamma[lane] + beta[lane] + x[(size_t)row * 64 + lane];
}

// ---------------------------------------------------------------------------
extern "C" void kernel_launch(void* const* d_in, const int* in_sizes, int n_in,
                              void* d_out, int out_size, void* d_ws, size_t ws_size,
                              hipStream_t stream) {
    const float* x   = (const float*)d_in[0];
    const int*   ei  = (const int*)  d_in[1];   // [2,E] flat: rows then cols
    const float* ew  = (const float*)d_in[2];
    const float* W   = (const float*)d_in[3];
    const float* b   = (const float*)d_in[4];
    const float* g   = (const float*)d_in[5];
    const float* bt  = (const float*)d_in[6];
    float* out = (float*)d_out;

    const int N = in_sizes[0] / 64;
    const int E = in_sizes[1] / 2;
    const int* rows = ei;
    const int* cols = ei + E;
    const int NB = (N + 1023) / 1024;

    // ws carve-up (8-byte aligned members first)
    char* w8 = (char*)d_ws;
    unsigned long long* packed = (unsigned long long*)w8; w8 += (size_t)N * 8;
    int2*           meta = (int2*)w8;                     w8 += (size_t)E * 8;
    unsigned short* xwb  = (unsigned short*)w8;           w8 += (size_t)N * 128;
    unsigned*       ord  = (unsigned*)w8;                 w8 += (size_t)E * 4;
    float*          dis  = (float*)w8;                    w8 += (size_t)N * 4;
    int*          rowptr = (int*)w8;                      w8 += (size_t)(N + 1) * 4;
    int*          bsums  = (int*)w8;                      w8 += (size_t)NB * 4;
    int*          boffs  = (int*)w8;

    k_init<<<(N + 255) / 256, 256, 0, stream>>>(packed, N);
    k_count_deg<<<(E + 255) / 256, 256, 0, stream>>>(rows, ew, packed, ord, E);
    k_scan1<<<NB, 256, 0, stream>>>(packed, bsums, N);
    k_scan2<<<1, 64, 0, stream>>>(bsums, boffs, rowptr, NB, N);
    k_scan3<<<NB, 256, 0, stream>>>(packed, boffs, rowptr, dis, N);
    k_fill<<<(E + 255) / 256, 256, 0, stream>>>(rows, cols, ew, ord, dis,
                                                rowptr, meta, E);

    // xw = x @ W^T (bf16): 1024 blocks x 4 waves
    const int xw_blocks = 512;
    const int xw_waves  = xw_blocks * 4;
    const int rpw = (N + xw_waves - 1) / xw_waves;
    k_xw<<<xw_blocks, 256, 0, stream>>>(x, W, xwb, N, rpw);

    long total = (long)N * 64;
    k_spmm_fused<<<(int)((total + 255) / 256), 256, 0, stream>>>(
        rowptr, meta, dis, xwb, x, b, g, bt, out, N);
}

// Round 7
// 226.505 us; speedup vs baseline: 1.2806x; 1.1841x over previous
//
#include <hip/hip_runtime.h>
#include <math.h>

#define DEG_EPS 1e-12f
#define LN_EPS  1e-5f

typedef __attribute__((ext_vector_type(8))) short bf16x8;
typedef __attribute__((ext_vector_type(4))) float f32x4;

__device__ __forceinline__ short f2bf(float f) {      // fp32 -> bf16 RNE
    unsigned u = __float_as_uint(f);
    u += 0x7FFF + ((u >> 16) & 1);
    return (short)(u >> 16);
}

// ---------------------------------------------------------------------------
// ws layout (8-byte aligned first):
//   packed : N * 8       (bits [55:40] = edge count, bits [39:0] = sum(ew)*2^24)
//   meta   : E * 8       (int2 {col, bitcast(nw)})
//   xwb    : N * 64 * 2  (bf16 xw = x @ W^T)
//   ord    : E * 4       (within-row ordinal of each edge)
//   dis    : N * 4       (rsqrt(deg+eps))
//   rowptr : (N+1)*4
//   bsums  : NB * 4
//   boffs  : NB * 4
// ---------------------------------------------------------------------------

__global__ __launch_bounds__(256) void k_init(unsigned long long* __restrict__ packed,
                                              int N) {
    int i = blockIdx.x * blockDim.x + threadIdx.x;
    if (i < N) packed[i] = 0ULL;
}

// one 64-bit atomic per edge: count + fixed-point deg; return gives ordinal
__global__ __launch_bounds__(256) void k_count_deg(const int* __restrict__ rows,
                                                   const float* __restrict__ ew,
                                                   unsigned long long* __restrict__ packed,
                                                   unsigned* __restrict__ ord, int E) {
    int e = blockIdx.x * blockDim.x + threadIdx.x;
    if (e < E) {
        int r = rows[e];
        unsigned long long fx = (unsigned long long)__float2uint_rn(ew[e] * 16777216.0f);
        unsigned long long old = atomicAdd(&packed[r], (1ULL << 40) | fx);
        ord[e] = (unsigned)(old >> 40);
    }
}

// per-block (1024 rows) count reduction -> bsums
__global__ __launch_bounds__(256) void k_scan1(const unsigned long long* __restrict__ packed,
                                               int* __restrict__ bsums, int N) {
    __shared__ int sc[256];
    int t = threadIdx.x, b = blockIdx.x;
    int base = b * 1024 + t * 4;
    int s = 0;
#pragma unroll
    for (int k = 0; k < 4; ++k) {
        int i = base + k;
        if (i < N) s += (int)(packed[i] >> 40);
    }
    sc[t] = s; __syncthreads();
    for (int off = 128; off > 0; off >>= 1) {
        if (t < off) sc[t] += sc[t + off];
        __syncthreads();
    }
    if (t == 0) bsums[b] = sc[0];
}

// serial exclusive scan of block sums (NB ~ 98)
__global__ void k_scan2(const int* __restrict__ bsums, int* __restrict__ boffs,
                        int* __restrict__ rowptr, int NB, int N) {
    if (threadIdx.x == 0 && blockIdx.x == 0) {
        int run = 0;
        for (int b = 0; b < NB; ++b) { boffs[b] = run; run += bsums[b]; }
        rowptr[N] = run;   // == E
    }
}

// block scan -> rowptr (exclusive); dis = rsqrt(deg+eps) from packed low bits
__global__ __launch_bounds__(256) void k_scan3(const unsigned long long* __restrict__ packed,
                                               const int* __restrict__ boffs,
                                               int* __restrict__ rowptr,
                                               float* __restrict__ dis, int N) {
    __shared__ int sc[256];
    int t = threadIdx.x, b = blockIdx.x;
    int base = b * 1024 + t * 4;
    int c[4]; int s = 0;
#pragma unroll
    for (int k = 0; k < 4; ++k) {
        int i = base + k;
        unsigned long long p = (i < N) ? packed[i] : 0ULL;
        c[k] = (int)(p >> 40);
        s += c[k];
        if (i < N) {
            double deg = 1.0 + (double)(p & 0xFFFFFFFFFFULL) * (1.0 / 16777216.0);
            dis[i] = rsqrtf((float)deg + DEG_EPS);
        }
    }
    sc[t] = s; __syncthreads();
    int mySum = s;
    for (int off = 1; off < 256; off <<= 1) {
        int v = (t >= off) ? sc[t - off] : 0;
        __syncthreads();
        sc[t] += v;
        __syncthreads();
    }
    int run = sc[t] - mySum + boffs[b];
#pragma unroll
    for (int k = 0; k < 4; ++k) {
        int i = base + k;
        if (i < N) rowptr[i] = run;
        run += c[k];
    }
}

// fill CSR — atomic-free: slot = rowptr[r] + ord[e]
__global__ __launch_bounds__(256) void k_fill(const int* __restrict__ rows,
                                              const int* __restrict__ cols,
                                              const float* __restrict__ ew,
                                              const unsigned* __restrict__ ord,
                                              const float* __restrict__ dis,
                                              const int* __restrict__ rowptr,
                                              int2* __restrict__ meta, int E) {
    int e = blockIdx.x * blockDim.x + threadIdx.x;
    if (e < E) {
        int r = rows[e], c = cols[e];
        float nw = ew[e] * dis[r] * dis[c];
        int slot = rowptr[r] + (int)ord[e];
        meta[slot] = make_int2(c, __float_as_int(nw));
    }
}

// ---------------------------------------------------------------------------
// xw = x @ W^T via MFMA (bf16 in, fp32 acc, bf16 out).
//   One wave computes a 16-node x 64-feature strip:
//     A frag: x[n0+m][s*32 + q*8 + j]   (m=lane&15, q=lane>>4, j=0..7)
//     B frag: W[tile*16+m][s*32+q*8+j]  (B = W^T so B^T = W, same loader)
//     D tile: node = n0 + q*4 + r, feat = tile*16 + m
//   W frags loaded once per wave; x via two float4 loads per K-step.
// ---------------------------------------------------------------------------
__global__ __launch_bounds__(256) void k_xw_mfma(const float* __restrict__ x,
                                                 const float* __restrict__ W,
                                                 unsigned short* __restrict__ xwb,
                                                 int Ntiles, int N) {
    const int lane = threadIdx.x & 63;
    const int m = lane & 15;
    const int q = lane >> 4;
    const int wave = (blockIdx.x * 256 + threadIdx.x) >> 6;
    const int nwaves = gridDim.x * 4;

    // B fragments (W rows), loaded once
    bf16x8 bfrag[4][2];
#pragma unroll
    for (int tile = 0; tile < 4; ++tile)
#pragma unroll
        for (int s = 0; s < 2; ++s) {
            const float4* wp = (const float4*)(W + (tile * 16 + m) * 64 + s * 32 + q * 8);
            float4 lo = wp[0], hi = wp[1];
            bf16x8 v;
            v[0] = f2bf(lo.x); v[1] = f2bf(lo.y); v[2] = f2bf(lo.z); v[3] = f2bf(lo.w);
            v[4] = f2bf(hi.x); v[5] = f2bf(hi.y); v[6] = f2bf(hi.z); v[7] = f2bf(hi.w);
            bfrag[tile][s] = v;
        }

    for (int t = wave; t < Ntiles; t += nwaves) {
        const int n0 = t * 16;
        const int nrow = n0 + m;
        const int nclamp = nrow < N ? nrow : N - 1;

        bf16x8 afrag[2];
#pragma unroll
        for (int s = 0; s < 2; ++s) {
            const float4* xp = (const float4*)(x + (size_t)nclamp * 64 + s * 32 + q * 8);
            float4 lo = xp[0], hi = xp[1];
            bf16x8 v;
            v[0] = f2bf(lo.x); v[1] = f2bf(lo.y); v[2] = f2bf(lo.z); v[3] = f2bf(lo.w);
            v[4] = f2bf(hi.x); v[5] = f2bf(hi.y); v[6] = f2bf(hi.z); v[7] = f2bf(hi.w);
            afrag[s] = v;
        }

#pragma unroll
        for (int tile = 0; tile < 4; ++tile) {
            f32x4 acc = {0.f, 0.f, 0.f, 0.f};
            acc = __builtin_amdgcn_mfma_f32_16x16x32_bf16(afrag[0], bfrag[tile][0], acc, 0, 0, 0);
            acc = __builtin_amdgcn_mfma_f32_16x16x32_bf16(afrag[1], bfrag[tile][1], acc, 0, 0, 0);
#pragma unroll
            for (int r = 0; r < 4; ++r) {
                int node = n0 + q * 4 + r;
                if (node < N)
                    xwb[(size_t)node * 64 + tile * 16 + m] = (unsigned short)f2bf(acc[r]);
            }
        }
    }
}

// ---------------------------------------------------------------------------
// Fused SpMM + bias + GELU + LayerNorm + residual.  One wave per row.
//   z[row][lane] = s^2*xw[row][lane] + sum_e nw_e * xw[col_e][lane]
//   out = LN(gelu(z + b)) * gamma + beta + x
// ---------------------------------------------------------------------------
__global__ __launch_bounds__(256) void k_spmm_fused(
    const int* __restrict__ rowptr, const int2* __restrict__ meta,
    const float* __restrict__ dis, const unsigned short* __restrict__ xwb,
    const float* __restrict__ x, const float* __restrict__ bias,
    const float* __restrict__ gamma, const float* __restrict__ beta,
    float* __restrict__ out, int N)
{
    int t = blockIdx.x * blockDim.x + threadIdx.x;
    int row = t >> 6;
    if (row >= N) return;
    int lane = t & 63;

    float s = dis[row];   // wave-uniform
    float acc = __uint_as_float((unsigned)xwb[(size_t)row * 64 + lane] << 16) * (s * s);

    int start = rowptr[row], end = rowptr[row + 1];
    for (int base = start; base < end; base += 64) {
        int rem = end - base;
        int cnt = rem < 64 ? rem : 64;
        int2 m = make_int2(0, 0);
        if (lane < rem) m = meta[base + lane];   // 64 edges, one coalesced load
        int j = 0;
        for (; j + 4 <= cnt; j += 4) {
            int   c0 = __shfl(m.x, j + 0, 64);
            float w0 = __int_as_float(__shfl(m.y, j + 0, 64));
            int   c1 = __shfl(m.x, j + 1, 64);
            float w1 = __int_as_float(__shfl(m.y, j + 1, 64));
            int   c2 = __shfl(m.x, j + 2, 64);
            float w2 = __int_as_float(__shfl(m.y, j + 2, 64));
            int   c3 = __shfl(m.x, j + 3, 64);
            float w3 = __int_as_float(__shfl(m.y, j + 3, 64));
            float v0 = __uint_as_float((unsigned)xwb[(size_t)c0 * 64 + lane] << 16);
            float v1 = __uint_as_float((unsigned)xwb[(size_t)c1 * 64 + lane] << 16);
            float v2 = __uint_as_float((unsigned)xwb[(size_t)c2 * 64 + lane] << 16);
            float v3 = __uint_as_float((unsigned)xwb[(size_t)c3 * 64 + lane] << 16);
            acc = fmaf(v0, w0, acc);
            acc = fmaf(v1, w1, acc);
            acc = fmaf(v2, w2, acc);
            acc = fmaf(v3, w3, acc);
        }
        for (; j < cnt; ++j) {
            int   c = __shfl(m.x, j, 64);
            float w = __int_as_float(__shfl(m.y, j, 64));
            acc = fmaf(__uint_as_float((unsigned)xwb[(size_t)c * 64 + lane] << 16),
                       w, acc);
        }
    }

    // --- fused epilogue, all in-wave ---
    float a = acc + bias[lane];
    a = 0.5f * a * (1.0f + erff(a * 0.70710678118654752f));   // exact gelu

    float sum = a, ssq = a * a;
#pragma unroll
    for (int mk = 1; mk < 64; mk <<= 1) {
        sum += __shfl_xor(sum, mk, 64);
        ssq += __shfl_xor(ssq, mk, 64);
    }
    float mean = sum * (1.0f / 64.0f);
    float var  = fmaxf(ssq * (1.0f / 64.0f) - mean * mean, 0.0f);
    float rs   = rsqrtf(var + LN_EPS);

    out[(size_t)row * 64 + lane] =
        (a - mean) * rs * gamma[lane] + beta[lane] + x[(size_t)row * 64 + lane];
}

// ---------------------------------------------------------------------------
extern "C" void kernel_launch(void* const* d_in, const int* in_sizes, int n_in,
                              void* d_out, int out_size, void* d_ws, size_t ws_size,
                              hipStream_t stream) {
    const float* x   = (const float*)d_in[0];
    const int*   ei  = (const int*)  d_in[1];   // [2,E] flat: rows then cols
    const float* ew  = (const float*)d_in[2];
    const float* W   = (const float*)d_in[3];
    const float* b   = (const float*)d_in[4];
    const float* g   = (const float*)d_in[5];
    const float* bt  = (const float*)d_in[6];
    float* out = (float*)d_out;

    const int N = in_sizes[0] / 64;
    const int E = in_sizes[1] / 2;
    const int* rows = ei;
    const int* cols = ei + E;
    const int NB = (N + 1023) / 1024;

    // ws carve-up (8-byte aligned members first)
    char* w8 = (char*)d_ws;
    unsigned long long* packed = (unsigned long long*)w8; w8 += (size_t)N * 8;
    int2*           meta = (int2*)w8;                     w8 += (size_t)E * 8;
    unsigned short* xwb  = (unsigned short*)w8;           w8 += (size_t)N * 128;
    unsigned*       ord  = (unsigned*)w8;                 w8 += (size_t)E * 4;
    float*          dis  = (float*)w8;                    w8 += (size_t)N * 4;
    int*          rowptr = (int*)w8;                      w8 += (size_t)(N + 1) * 4;
    int*          bsums  = (int*)w8;                      w8 += (size_t)NB * 4;
    int*          boffs  = (int*)w8;

    k_init<<<(N + 255) / 256, 256, 0, stream>>>(packed, N);
    k_count_deg<<<(E + 255) / 256, 256, 0, stream>>>(rows, ew, packed, ord, E);
    k_scan1<<<NB, 256, 0, stream>>>(packed, bsums, N);
    k_scan2<<<1, 64, 0, stream>>>(bsums, boffs, rowptr, NB, N);
    k_scan3<<<NB, 256, 0, stream>>>(packed, boffs, rowptr, dis, N);
    k_fill<<<(E + 255) / 256, 256, 0, stream>>>(rows, cols, ew, ord, dis,
                                                rowptr, meta, E);

    // xw = x @ W^T via MFMA: 16-node tiles
    const int Ntiles = (N + 15) / 16;
    k_xw_mfma<<<1024, 256, 0, stream>>>(x, W, xwb, Ntiles, N);

    long total = (long)N * 64;
    k_spmm_fused<<<(int)((total + 255) / 256), 256, 0, stream>>>(
        rowptr, meta, dis, xwb, x, b, g, bt, out, N);
}